// Round 1
// baseline (112.501 us; speedup 1.0000x reference)
//
#include <hip/hip_runtime.h>

namespace {

constexpr int Bq = 32;    // batch
constexpr int Tq = 128;   // seq len == #scan steps (i) == softmax axis (t)
constexpr int Fq = 128;   // feature dim
constexpr int Uq = 128;   // unit dim
constexpr int PITCH = 129;  // odd pitch -> conflict-free column-ish access

__device__ __forceinline__ float sigmoid_(float x) {
  return 1.0f / (1.0f + __expf(-x));
}
__device__ __forceinline__ float tanh_(float x) {
  x = fminf(20.0f, fmaxf(-20.0f, x));
  const float e = __expf(2.0f * x);
  return (e - 1.0f) / (e + 1.0f);
}

// ---------------------------------------------------------------------------
// K1: alphas.  P[b][t][i] = softmax_t( sum_f X[b,t,f] * Wd[f,i] )
// grid(4, 32): x = i-tile (32 i), y = b.  256 threads.
// Wave layout: lanes hold t = lane and t = lane+64 (all 128 t per wave),
// i-octet (i0..i0+7) is wave-uniform -> Wd reads become scalar loads.
// Softmax over t = full-wave shfl_xor butterfly (no LDS round trip).
// ---------------------------------------------------------------------------
__global__ __launch_bounds__(256) void k_alphas(const float* __restrict__ X,
                                                const float* __restrict__ Wd,
                                                float* __restrict__ P) {
  __shared__ float Xs[Tq * PITCH];
  const int tid = threadIdx.x;
  const int b = blockIdx.y;
  const float* Xb = X + b * (Tq * Fq);
#pragma unroll
  for (int it = 0; it < 16; ++it) {
    const int e = tid + it * 256;
    const int t = e >> 5;      // 32 float4 per 128-float row
    const int f4 = e & 31;
    const float4 v = reinterpret_cast<const float4*>(Xb)[e];
    float* d = &Xs[t * PITCH + f4 * 4];
    d[0] = v.x; d[1] = v.y; d[2] = v.z; d[3] = v.w;
  }
  __syncthreads();

  const int lane = tid & 63;
  const int wv = tid >> 6;
  const int i0 = __builtin_amdgcn_readfirstlane((int)(blockIdx.x * 32u) + wv * 8);

  float a0[8], a1[8];
#pragma unroll
  for (int j = 0; j < 8; ++j) { a0[j] = 0.0f; a1[j] = 0.0f; }

  const float* Wp = Wd + i0;              // Wd[f][i] at f*Tq + i (top F rows only)
  const float* xr0 = &Xs[lane * PITCH];
  const float* xr1 = &Xs[(lane + 64) * PITCH];
  for (int f = 0; f < Fq; ++f) {
    const float x0 = xr0[f];
    const float x1 = xr1[f];
    const float* wr = Wp + f * Tq;        // uniform address -> s_load
#pragma unroll
    for (int j = 0; j < 8; ++j) {
      const float w = wr[j];
      a0[j] = fmaf(x0, w, a0[j]);
      a1[j] = fmaf(x1, w, a1[j]);
    }
  }

  // softmax over t: this wave holds all 128 t for its 8 i-columns
  float p0[8], p1[8];
#pragma unroll
  for (int j = 0; j < 8; ++j) {
    float m = fmaxf(a0[j], a1[j]);
#pragma unroll
    for (int d = 1; d < 64; d <<= 1) m = fmaxf(m, __shfl_xor(m, d, 64));
    const float e0 = __expf(a0[j] - m);
    const float e1 = __expf(a1[j] - m);
    float s = e0 + e1;
#pragma unroll
    for (int d = 1; d < 64; d <<= 1) s += __shfl_xor(s, d, 64);
    const float inv = 1.0f / s;
    p0[j] = e0 * inv;
    p1[j] = e1 * inv;
  }

  float* P0 = P + ((b * Tq + lane) * Tq + i0);
  float* P1 = P + ((b * Tq + lane + 64) * Tq + i0);
  reinterpret_cast<float4*>(P0)[0] = make_float4(p0[0], p0[1], p0[2], p0[3]);
  reinterpret_cast<float4*>(P0)[1] = make_float4(p0[4], p0[5], p0[6], p0[7]);
  reinterpret_cast<float4*>(P1)[0] = make_float4(p1[0], p1[1], p1[2], p1[3]);
  reinterpret_cast<float4*>(P1)[1] = make_float4(p1[4], p1[5], p1[6], p1[7]);
}

// ---------------------------------------------------------------------------
// K2: context.  C[b][i][f] = sum_t P[b][t][i] * X[b][t][f]
// grid(4, 32): x = f-tile (32 f), y = b.  256 threads.
// Lanes hold i = lane, lane+64; f-octet wave-uniform -> X reads scalar.
// ---------------------------------------------------------------------------
__global__ __launch_bounds__(256) void k_ctx(const float* __restrict__ P,
                                             const float* __restrict__ X,
                                             float* __restrict__ C) {
  __shared__ float Ps[Tq * PITCH];
  const int tid = threadIdx.x;
  const int b = blockIdx.y;
  const float* Pb = P + b * (Tq * Tq);
#pragma unroll
  for (int it = 0; it < 16; ++it) {
    const int e = tid + it * 256;
    const int t = e >> 5;
    const int i4 = e & 31;
    const float4 v = reinterpret_cast<const float4*>(Pb)[e];
    float* d = &Ps[t * PITCH + i4 * 4];
    d[0] = v.x; d[1] = v.y; d[2] = v.z; d[3] = v.w;
  }
  __syncthreads();

  const int lane = tid & 63;
  const int wv = tid >> 6;
  const int f0 = __builtin_amdgcn_readfirstlane((int)(blockIdx.x * 32u) + wv * 8);

  float a0[8], a1[8];
#pragma unroll
  for (int j = 0; j < 8; ++j) { a0[j] = 0.0f; a1[j] = 0.0f; }

  const float* Xp = X + b * (Tq * Fq) + f0;
  for (int t = 0; t < Tq; ++t) {
    const float q0 = Ps[t * PITCH + lane];        // conflict-free (consecutive)
    const float q1 = Ps[t * PITCH + lane + 64];
    const float* xr = Xp + t * Fq;                // uniform -> s_load
#pragma unroll
    for (int j = 0; j < 8; ++j) {
      const float xw = xr[j];
      a0[j] = fmaf(q0, xw, a0[j]);
      a1[j] = fmaf(q1, xw, a1[j]);
    }
  }

  float* C0 = C + ((b * Tq + lane) * Fq + f0);
  float* C1 = C + ((b * Tq + lane + 64) * Fq + f0);
  reinterpret_cast<float4*>(C0)[0] = make_float4(a0[0], a0[1], a0[2], a0[3]);
  reinterpret_cast<float4*>(C0)[1] = make_float4(a0[4], a0[5], a0[6], a0[7]);
  reinterpret_cast<float4*>(C1)[0] = make_float4(a1[0], a1[1], a1[2], a1[3]);
  reinterpret_cast<float4*>(C1)[1] = make_float4(a1[4], a1[5], a1[6], a1[7]);
}

// ---------------------------------------------------------------------------
// K3: gates + activation.  z = C @ Wk + bl (gates i, c, o only; f-gate and Wr
// are dead because h0 = c0 = 0).  out[b][i][u] = sig(zo)*tanh(sig(zi)*tanh(zc))
// grid(32, 8): x = b, y = u-tile (16 u).  256 threads.
// Lanes hold rows i = lane, lane+64; u-quad wave-uniform -> Wk reads scalar.
// ---------------------------------------------------------------------------
__global__ __launch_bounds__(256) void k_out(const float* __restrict__ C,
                                             const float* __restrict__ Wk,
                                             const float* __restrict__ bl,
                                             float* __restrict__ out) {
  __shared__ float Cs[Tq * PITCH];
  const int tid = threadIdx.x;
  const int b = blockIdx.x;
  const float* Cb = C + b * (Tq * Fq);
#pragma unroll
  for (int it = 0; it < 16; ++it) {
    const int e = tid + it * 256;
    const int i = e >> 5;
    const int f4 = e & 31;
    const float4 v = reinterpret_cast<const float4*>(Cb)[e];
    float* d = &Cs[i * PITCH + f4 * 4];
    d[0] = v.x; d[1] = v.y; d[2] = v.z; d[3] = v.w;
  }
  __syncthreads();

  const int lane = tid & 63;
  const int wv = tid >> 6;
  const int u0 = __builtin_amdgcn_readfirstlane((int)(blockIdx.y * 16u) + wv * 4);

  float ai0[4] = {0.f, 0.f, 0.f, 0.f}, ai1[4] = {0.f, 0.f, 0.f, 0.f};
  float ac0[4] = {0.f, 0.f, 0.f, 0.f}, ac1[4] = {0.f, 0.f, 0.f, 0.f};
  float ao0[4] = {0.f, 0.f, 0.f, 0.f}, ao1[4] = {0.f, 0.f, 0.f, 0.f};

  const float* Wp = Wk + u0;              // Wk[f][n] at f*4U + n
  const float* cr0 = &Cs[lane * PITCH];
  const float* cr1 = &Cs[(lane + 64) * PITCH];
  for (int f = 0; f < Fq; ++f) {
    const float c0 = cr0[f];
    const float c1 = cr1[f];
    const float* wr = Wp + f * (4 * Uq);  // uniform -> s_load
#pragma unroll
    for (int j = 0; j < 4; ++j) {
      const float wi = wr[j];
      const float wc = wr[2 * Uq + j];
      const float wo = wr[3 * Uq + j];
      ai0[j] = fmaf(c0, wi, ai0[j]); ai1[j] = fmaf(c1, wi, ai1[j]);
      ac0[j] = fmaf(c0, wc, ac0[j]); ac1[j] = fmaf(c1, wc, ac1[j]);
      ao0[j] = fmaf(c0, wo, ao0[j]); ao1[j] = fmaf(c1, wo, ao1[j]);
    }
  }

  float h0[4], h1[4];
#pragma unroll
  for (int j = 0; j < 4; ++j) {
    const float bi = bl[u0 + j];
    const float bc = bl[2 * Uq + u0 + j];
    const float bo = bl[3 * Uq + u0 + j];
    const float cc0 = sigmoid_(ai0[j] + bi) * tanh_(ac0[j] + bc);
    h0[j] = sigmoid_(ao0[j] + bo) * tanh_(cc0);
    const float cc1 = sigmoid_(ai1[j] + bi) * tanh_(ac1[j] + bc);
    h1[j] = sigmoid_(ao1[j] + bo) * tanh_(cc1);
  }

  float* O0 = out + ((b * Tq + lane) * Uq + u0);
  float* O1 = out + ((b * Tq + lane + 64) * Uq + u0);
  reinterpret_cast<float4*>(O0)[0] = make_float4(h0[0], h0[1], h0[2], h0[3]);
  reinterpret_cast<float4*>(O1)[0] = make_float4(h1[0], h1[1], h1[2], h1[3]);
}

}  // namespace

extern "C" void kernel_launch(void* const* d_in, const int* in_sizes, int n_in,
                              void* d_out, int out_size, void* d_ws, size_t ws_size,
                              hipStream_t stream) {
  const float* X  = (const float*)d_in[0];   // (B, T, F)
  const float* Wd = (const float*)d_in[1];   // (F+U, T); only rows [0,F) matter
  // d_in[2] = bd: constant along softmax axis -> cancels, unused
  const float* Wk = (const float*)d_in[3];   // (F, 4U)
  // d_in[4] = Wr: multiplied by h0 == 0 -> unused
  const float* bl = (const float*)d_in[5];   // (4U,)
  float* out = (float*)d_out;                // (B, T, U) fp32

  float* P = (float*)d_ws;                   // (B, T, T)  alphas, t-major
  float* C = P + Bq * Tq * Tq;               // (B, T, F)  contexts

  k_alphas<<<dim3(4, 32), 256, 0, stream>>>(X, Wd, P);
  k_ctx<<<dim3(4, 32), 256, 0, stream>>>(P, X, C);
  k_out<<<dim3(32, 8), 256, 0, stream>>>(C, Wk, bl, out);
}

// Round 2
// 103.160 us; speedup vs baseline: 1.0905x; 1.0905x over previous
//
#include <hip/hip_runtime.h>

namespace {

constexpr int Bq = 32;    // batch
constexpr int Tq = 128;   // seq len == #scan steps (i) == softmax axis (t)
constexpr int Fq = 128;   // feature dim
constexpr int Uq = 128;   // unit dim
constexpr int PITCH = 129;   // Xs pitch: odd -> conflict-free row/col access
constexpr int APITCH = 17;   // As pitch: 16 i_local + 1 pad

__device__ __forceinline__ float sigmoid_(float x) {
  return 1.0f / (1.0f + __expf(-x));
}
__device__ __forceinline__ float tanh_(float x) {
  x = fminf(20.0f, fmaxf(-20.0f, x));
  const float e = __expf(2.0f * x);
  return (e - 1.0f) / (e + 1.0f);
}

// ---------------------------------------------------------------------------
// KF: fused alphas + context.
//   logits L[t,i] = sum_f X[b,t,f] * Wd[f,i]      (Wd top F rows only;
//     bd and the carry s cancel under softmax over t)
//   alpha = softmax_t(L);  C[b,i,f] = sum_t alpha[t,i] * X[b,t,f]
// grid(8, 32): x = i-tile (16 i), y = b.  256 threads = 4 waves.
// Each wave owns 4 consecutive i.
//   Stage 1: lanes <-> t (t = lane, lane+64), Wd quad s_loaded (uniform).
//   softmax: full-wave shfl_xor butterfly (wave holds all 128 t).
//   alpha transposed via LDS As[t][i_local] (float4 per lane, pitch 17).
//   Stage 2: lanes <-> f (f = lane, lane+64), alpha quad broadcast from LDS.
// ---------------------------------------------------------------------------
__global__ __launch_bounds__(256) void k_fused(const float* __restrict__ X,
                                               const float* __restrict__ Wd,
                                               float* __restrict__ C) {
  __shared__ float Xs[Tq * PITCH];   // 64.5 KB
  __shared__ float As[Tq * APITCH];  // 8.7 KB
  const int tid = threadIdx.x;
  const int b = blockIdx.y;
  const float* Xb = X + b * (Tq * Fq);
#pragma unroll
  for (int it = 0; it < 16; ++it) {
    const int e = tid + it * 256;
    const int t = e >> 5;      // 32 float4 per 128-float row
    const int f4 = e & 31;
    const float4 v = reinterpret_cast<const float4*>(Xb)[e];
    float* d = &Xs[t * PITCH + f4 * 4];
    d[0] = v.x; d[1] = v.y; d[2] = v.z; d[3] = v.w;
  }
  __syncthreads();

  const int lane = tid & 63;
  const int wv = tid >> 6;
  const int iL = wv * 4;  // i_local base of this wave
  const int i0 = __builtin_amdgcn_readfirstlane((int)(blockIdx.x * 16u) + iL);

  // ---- stage 1: logits for i0..i0+3 at t = lane, lane+64 ----
  float a0[4] = {0.f, 0.f, 0.f, 0.f}, a1[4] = {0.f, 0.f, 0.f, 0.f};
  const float* Wp = Wd + i0;              // Wd[f][i] at f*Tq + i
  const float* xr0 = &Xs[lane * PITCH];
  const float* xr1 = &Xs[(lane + 64) * PITCH];
#pragma unroll 8
  for (int f = 0; f < Fq; ++f) {
    const float x0 = xr0[f];
    const float x1 = xr1[f];
    const float* wr = Wp + f * Tq;        // uniform -> s_load_dwordx4
#pragma unroll
    for (int j = 0; j < 4; ++j) {
      const float w = wr[j];
      a0[j] = fmaf(x0, w, a0[j]);
      a1[j] = fmaf(x1, w, a1[j]);
    }
  }

  // ---- softmax over t (whole wave) ----
  float p0[4], p1[4];
#pragma unroll
  for (int j = 0; j < 4; ++j) {
    float m = fmaxf(a0[j], a1[j]);
#pragma unroll
    for (int d = 1; d < 64; d <<= 1) m = fmaxf(m, __shfl_xor(m, d, 64));
    const float e0 = __expf(a0[j] - m);
    const float e1 = __expf(a1[j] - m);
    float s = e0 + e1;
#pragma unroll
    for (int d = 1; d < 64; d <<= 1) s += __shfl_xor(s, d, 64);
    const float inv = 1.0f / s;
    p0[j] = e0 * inv;
    p1[j] = e1 * inv;
  }

  // ---- transpose alpha through LDS: As[t][iL..iL+3] ----
  *reinterpret_cast<float4*>(&As[lane * APITCH + iL]) =
      make_float4(p0[0], p0[1], p0[2], p0[3]);
  *reinterpret_cast<float4*>(&As[(lane + 64) * APITCH + iL]) =
      make_float4(p1[0], p1[1], p1[2], p1[3]);
  __syncthreads();  // cheap; guarantees LDS RAW ordering

  // ---- stage 2: C[i, f] = sum_t alpha[t,i] * X[t,f]; lanes <-> f ----
  float c0[4] = {0.f, 0.f, 0.f, 0.f}, c1[4] = {0.f, 0.f, 0.f, 0.f};
#pragma unroll 8
  for (int t = 0; t < Tq; ++t) {
    const float4 a4 = *reinterpret_cast<const float4*>(&As[t * APITCH + iL]);
    const float aa[4] = {a4.x, a4.y, a4.z, a4.w};  // broadcast reads
    const float x0 = Xs[t * PITCH + lane];
    const float x1 = Xs[t * PITCH + lane + 64];
#pragma unroll
    for (int j = 0; j < 4; ++j) {
      c0[j] = fmaf(aa[j], x0, c0[j]);
      c1[j] = fmaf(aa[j], x1, c1[j]);
    }
  }

#pragma unroll
  for (int j = 0; j < 4; ++j) {
    float* cp = C + (b * Tq + i0 + j) * Fq;
    cp[lane] = c0[j];
    cp[lane + 64] = c1[j];
  }
}

// ---------------------------------------------------------------------------
// K3: gates + activation.  z = C @ Wk + bl (gates i, c, o only; f-gate and Wr
// are dead because h0 = c0 = 0).  out[b][i][u] = sig(zo)*tanh(sig(zi)*tanh(zc))
// grid(32, 8): x = b, y = u-tile (16 u).  256 threads = 4 waves.
// Lanes hold rows i = lane, lane+64; u-quad wave-uniform -> Wk s_loads.
// ---------------------------------------------------------------------------
__global__ __launch_bounds__(256) void k_out(const float* __restrict__ C,
                                             const float* __restrict__ Wk,
                                             const float* __restrict__ bl,
                                             float* __restrict__ out) {
  __shared__ float Cs[Tq * PITCH];
  const int tid = threadIdx.x;
  const int b = blockIdx.x;
  const float* Cb = C + b * (Tq * Fq);
#pragma unroll
  for (int it = 0; it < 16; ++it) {
    const int e = tid + it * 256;
    const int i = e >> 5;
    const int f4 = e & 31;
    const float4 v = reinterpret_cast<const float4*>(Cb)[e];
    float* d = &Cs[i * PITCH + f4 * 4];
    d[0] = v.x; d[1] = v.y; d[2] = v.z; d[3] = v.w;
  }
  __syncthreads();

  const int lane = tid & 63;
  const int wv = tid >> 6;
  const int u0 = __builtin_amdgcn_readfirstlane((int)(blockIdx.y * 16u) + wv * 4);

  float ai0[4] = {0.f, 0.f, 0.f, 0.f}, ai1[4] = {0.f, 0.f, 0.f, 0.f};
  float ac0[4] = {0.f, 0.f, 0.f, 0.f}, ac1[4] = {0.f, 0.f, 0.f, 0.f};
  float ao0[4] = {0.f, 0.f, 0.f, 0.f}, ao1[4] = {0.f, 0.f, 0.f, 0.f};

  const float* Wp = Wk + u0;              // Wk[f][n] at f*4U + n
  const float* cr0 = &Cs[lane * PITCH];
  const float* cr1 = &Cs[(lane + 64) * PITCH];
#pragma unroll 8
  for (int f = 0; f < Fq; ++f) {
    const float c0 = cr0[f];
    const float c1 = cr1[f];
    const float* wr = Wp + f * (4 * Uq);  // uniform -> s_load_dwordx4 x3
#pragma unroll
    for (int j = 0; j < 4; ++j) {
      const float wi = wr[j];
      const float wc = wr[2 * Uq + j];
      const float wo = wr[3 * Uq + j];
      ai0[j] = fmaf(c0, wi, ai0[j]); ai1[j] = fmaf(c1, wi, ai1[j]);
      ac0[j] = fmaf(c0, wc, ac0[j]); ac1[j] = fmaf(c1, wc, ac1[j]);
      ao0[j] = fmaf(c0, wo, ao0[j]); ao1[j] = fmaf(c1, wo, ao1[j]);
    }
  }

  float h0[4], h1[4];
#pragma unroll
  for (int j = 0; j < 4; ++j) {
    const float bi = bl[u0 + j];
    const float bc = bl[2 * Uq + u0 + j];
    const float bo = bl[3 * Uq + u0 + j];
    const float cc0 = sigmoid_(ai0[j] + bi) * tanh_(ac0[j] + bc);
    h0[j] = sigmoid_(ao0[j] + bo) * tanh_(cc0);
    const float cc1 = sigmoid_(ai1[j] + bi) * tanh_(ac1[j] + bc);
    h1[j] = sigmoid_(ao1[j] + bo) * tanh_(cc1);
  }

  float* O0 = out + ((b * Tq + lane) * Uq + u0);
  float* O1 = out + ((b * Tq + lane + 64) * Uq + u0);
  reinterpret_cast<float4*>(O0)[0] = make_float4(h0[0], h0[1], h0[2], h0[3]);
  reinterpret_cast<float4*>(O1)[0] = make_float4(h1[0], h1[1], h1[2], h1[3]);
}

}  // namespace

extern "C" void kernel_launch(void* const* d_in, const int* in_sizes, int n_in,
                              void* d_out, int out_size, void* d_ws, size_t ws_size,
                              hipStream_t stream) {
  const float* X  = (const float*)d_in[0];   // (B, T, F)
  const float* Wd = (const float*)d_in[1];   // (F+U, T); only rows [0,F) matter
  // d_in[2] = bd: constant along softmax axis -> cancels, unused
  const float* Wk = (const float*)d_in[3];   // (F, 4U)
  // d_in[4] = Wr: multiplied by h0 == 0 -> unused
  const float* bl = (const float*)d_in[5];   // (4U,)
  float* out = (float*)d_out;                // (B, T, U) fp32

  float* C = (float*)d_ws;                   // (B, T, F) contexts

  k_fused<<<dim3(8, 32), 256, 0, stream>>>(X, Wd, C);
  k_out<<<dim3(32, 8), 256, 0, stream>>>(C, Wk, bl, out);
}

// Round 3
// 92.169 us; speedup vs baseline: 1.2206x; 1.1192x over previous
//
#include <hip/hip_runtime.h>

namespace {

constexpr int Bq = 32;    // batch
constexpr int Tq = 128;   // seq len == #scan steps (i) == softmax axis (t)
constexpr int Fq = 128;   // feature dim
constexpr int Uq = 128;   // unit dim
constexpr int PITCH  = 129;  // Xs pitch (odd -> conflict-free b32 row reads)
constexpr int APITCH = 20;   // As pitch: 16 i + 4 pad, keeps float4 16B-aligned
constexpr int CPITCH = 132;  // Cs pitch: 128 f + 4 pad, keeps float4 16B-aligned
constexpr int ITILE  = 16;   // i per block

__device__ __forceinline__ float sigmoid_(float x) {
  return 1.0f / (1.0f + __expf(-x));
}
__device__ __forceinline__ float tanh_(float x) {
  x = fminf(20.0f, fmaxf(-20.0f, x));
  const float e = __expf(2.0f * x);
  return (e - 1.0f) / (e + 1.0f);
}

// ---------------------------------------------------------------------------
// Fully fused: logits -> softmax -> context -> gates -> activations.
//   L[t,i]  = sum_f X[b,t,f] * Wd[f,i]        (bd and carry s cancel in softmax)
//   alpha   = softmax_t(L)
//   C[i,f]  = sum_t alpha[t,i] * X[b,t,f]     (kept in LDS)
//   z       = C @ Wk + bl  (gates i,c,o only; f-gate dead: c0=0; Wr dead: h0=0)
//   out[b,i,u] = sig(z_o) * tanh( sig(z_i) * tanh(z_c) )
// grid(8, 32): x = i-tile (16 i), y = b.  256 threads = 4 waves, 1 block/CU.
// ---------------------------------------------------------------------------
__global__ __launch_bounds__(256) void k_all(const float* __restrict__ X,
                                             const float* __restrict__ Wd,
                                             const float* __restrict__ Wk,
                                             const float* __restrict__ bl,
                                             float* __restrict__ out) {
  __shared__ float Xs[Tq * PITCH];       // 66.0 KB
  __shared__ float As[Tq * APITCH];      // 10.2 KB
  __shared__ float Cs[ITILE * CPITCH];   //  8.4 KB
  const int tid = threadIdx.x;
  const int b = blockIdx.y;
  const int i0b = blockIdx.x * ITILE;

  // ---- stage X[b] into LDS (row t contiguous, pitch 129) ----
  const float* Xb = X + b * (Tq * Fq);
#pragma unroll
  for (int it = 0; it < 16; ++it) {
    const int e = tid + it * 256;
    const int t = e >> 5;                // 32 float4 per 128-float row
    const int f4 = e & 31;
    const float4 v = reinterpret_cast<const float4*>(Xb)[e];
    float* d = &Xs[t * PITCH + f4 * 4];
    d[0] = v.x; d[1] = v.y; d[2] = v.z; d[3] = v.w;
  }
  __syncthreads();

  const int lane = tid & 63;
  const int wv = tid >> 6;
  const int iL = wv * 4;                 // wave's i_local base
  const int i0 = __builtin_amdgcn_readfirstlane(i0b + iL);

  // ---- stage 1: logits for i0..i0+3 at t = lane, lane+64 ----
  float a0[4] = {0.f, 0.f, 0.f, 0.f}, a1[4] = {0.f, 0.f, 0.f, 0.f};
  const float* Wp = Wd + i0;             // Wd[f][i] at f*Tq + i (top F rows)
  const float* xr0 = &Xs[lane * PITCH];
  const float* xr1 = &Xs[(lane + 64) * PITCH];
#pragma unroll 8
  for (int f = 0; f < Fq; ++f) {
    const float x0 = xr0[f];
    const float x1 = xr1[f];
    const float* wr = Wp + f * Tq;       // uniform -> s_load_dwordx4
#pragma unroll
    for (int j = 0; j < 4; ++j) {
      const float w = wr[j];
      a0[j] = fmaf(x0, w, a0[j]);
      a1[j] = fmaf(x1, w, a1[j]);
    }
  }

  // ---- softmax over t (wave holds all 128 t) ----
  float p0[4], p1[4];
#pragma unroll
  for (int j = 0; j < 4; ++j) {
    float m = fmaxf(a0[j], a1[j]);
#pragma unroll
    for (int d = 1; d < 64; d <<= 1) m = fmaxf(m, __shfl_xor(m, d, 64));
    const float e0 = __expf(a0[j] - m);
    const float e1 = __expf(a1[j] - m);
    float s = e0 + e1;
#pragma unroll
    for (int d = 1; d < 64; d <<= 1) s += __shfl_xor(s, d, 64);
    const float inv = 1.0f / s;
    p0[j] = e0 * inv;
    p1[j] = e1 * inv;
  }

  // ---- transpose alpha through LDS: As[t][iL..iL+3] (16B-aligned) ----
  *reinterpret_cast<float4*>(&As[lane * APITCH + iL]) =
      make_float4(p0[0], p0[1], p0[2], p0[3]);
  *reinterpret_cast<float4*>(&As[(lane + 64) * APITCH + iL]) =
      make_float4(p1[0], p1[1], p1[2], p1[3]);
  __syncthreads();

  // ---- stage 2: Cs[i_local][f] = sum_t alpha[t,i] * Xs[t][f]; lanes <-> f ----
  float c0[4] = {0.f, 0.f, 0.f, 0.f}, c1[4] = {0.f, 0.f, 0.f, 0.f};
#pragma unroll 8
  for (int t = 0; t < Tq; ++t) {
    const float4 a4 = *reinterpret_cast<const float4*>(&As[t * APITCH + iL]);
    const float aa[4] = {a4.x, a4.y, a4.z, a4.w};  // wave-uniform broadcast
    const float x0 = Xs[t * PITCH + lane];
    const float x1 = Xs[t * PITCH + lane + 64];
#pragma unroll
    for (int j = 0; j < 4; ++j) {
      c0[j] = fmaf(aa[j], x0, c0[j]);
      c1[j] = fmaf(aa[j], x1, c1[j]);
    }
  }
#pragma unroll
  for (int j = 0; j < 4; ++j) {
    Cs[(iL + j) * CPITCH + lane] = c0[j];
    Cs[(iL + j) * CPITCH + lane + 64] = c1[j];
  }
  __syncthreads();

  // ---- gate GEMM + activations.  thread -> (u = wv*32 + (lane&31),
  //      i-half = (lane>>5)*8): 8 rows x 1 col x 3 gates each ----
  const int uu = lane & 31;
  const int ih = (lane >> 5) * 8;
  const int ub = wv * 32 + uu;
  float zi[8], zc[8], zo[8];
#pragma unroll
  for (int j = 0; j < 8; ++j) { zi[j] = 0.f; zc[j] = 0.f; zo[j] = 0.f; }

  const float* WkP = Wk + ub;            // Wk[f][n] at f*4U + n
  for (int f = 0; f < Fq; f += 4) {
    float4 cr[8];
#pragma unroll
    for (int j = 0; j < 8; ++j)          // broadcast b128 reads (2 addrs/wave)
      cr[j] = *reinterpret_cast<const float4*>(&Cs[(ih + j) * CPITCH + f]);
#pragma unroll
    for (int ff = 0; ff < 4; ++ff) {
      const float* wf = WkP + (f + ff) * (4 * Uq);
      const float wi = wf[0];            // coalesced dword (32 consecutive u)
      const float wc = wf[2 * Uq];
      const float wo = wf[3 * Uq];
#pragma unroll
      for (int j = 0; j < 8; ++j) {
        const float cv = (&cr[j].x)[ff];
        zi[j] = fmaf(cv, wi, zi[j]);
        zc[j] = fmaf(cv, wc, zc[j]);
        zo[j] = fmaf(cv, wo, zo[j]);
      }
    }
  }

  const float bi = bl[ub];
  const float bc = bl[2 * Uq + ub];
  const float bo = bl[3 * Uq + ub];
#pragma unroll
  for (int j = 0; j < 8; ++j) {
    const float cc = sigmoid_(zi[j] + bi) * tanh_(zc[j] + bc);
    const float h = sigmoid_(zo[j] + bo) * tanh_(cc);
    out[(b * Tq + i0b + ih + j) * Uq + ub] = h;
  }
}

}  // namespace

extern "C" void kernel_launch(void* const* d_in, const int* in_sizes, int n_in,
                              void* d_out, int out_size, void* d_ws, size_t ws_size,
                              hipStream_t stream) {
  const float* X  = (const float*)d_in[0];   // (B, T, F)
  const float* Wd = (const float*)d_in[1];   // (F+U, T); only rows [0,F) matter
  // d_in[2] = bd: constant along softmax axis -> cancels, unused
  const float* Wk = (const float*)d_in[3];   // (F, 4U)
  // d_in[4] = Wr: multiplied by h0 == 0 -> unused
  const float* bl = (const float*)d_in[5];   // (4U,)
  float* out = (float*)d_out;                // (B, T, U) fp32

  k_all<<<dim3(8, 32), 256, 0, stream>>>(X, Wd, Wk, bl, out);
}

// Round 4
// 87.235 us; speedup vs baseline: 1.2896x; 1.0566x over previous
//
#include <hip/hip_runtime.h>

namespace {

constexpr int Bq = 32;    // batch
constexpr int Tq = 128;   // seq len == #scan steps (i) == softmax axis (t)
constexpr int Fq = 128;   // feature dim
constexpr int Uq = 128;   // unit dim
constexpr int PITCH  = 129;  // Xs pitch (odd -> conflict-free b32 row reads)
constexpr int APITCH = 20;   // As pitch: 16 i + 4 pad, keeps float2/4 aligned
constexpr int CPITCH = 132;  // Cs pitch: 128 f + 4 pad, keeps float4 16B-aligned
constexpr int ITILE  = 16;   // i per block

__device__ __forceinline__ float sigmoid_(float x) {
  return 1.0f / (1.0f + __expf(-x));
}
__device__ __forceinline__ float tanh_(float x) {
  x = fminf(20.0f, fmaxf(-20.0f, x));
  const float e = __expf(2.0f * x);
  return (e - 1.0f) / (e + 1.0f);
}

// ---------------------------------------------------------------------------
// Fully fused: logits -> softmax -> context -> gates -> activations.
//   L[t,i]  = sum_f X[b,t,f] * Wd[f,i]     (bd and carry s cancel in softmax)
//   alpha   = softmax_t(L)
//   C[i,f]  = sum_t alpha[t,i] * X[b,t,f]  (kept in LDS)
//   z       = C @ Wk + bl  (gates i,c,o only; f-gate dead: c0=0; Wr dead: h0=0)
//   out[b,i,u] = sig(z_o) * tanh( sig(z_i) * tanh(z_c) )
// grid(8, 32): x = i-tile (16 i), y = b.  512 threads = 8 waves -> 2 waves/SIMD
// (R3 was 4 waves -> 1/SIMD, VALUBusy 16%: pure latency bound; this doubles TLP
// at zero extra staging).  As/Cs share one LDS buffer (barrier-separated) to
// keep LDS at 74.5 KB.
// ---------------------------------------------------------------------------
__global__ __launch_bounds__(512) void k_all(const float* __restrict__ X,
                                             const float* __restrict__ Wd,
                                             const float* __restrict__ Wk,
                                             const float* __restrict__ bl,
                                             float* __restrict__ out) {
  __shared__ float Xs[Tq * PITCH];                       // 66.0 KB
  __shared__ float SB[Tq * APITCH > ITILE * CPITCH ?     //  8.5 KB (union:
                      Tq * APITCH : ITILE * CPITCH];     //  As then Cs)
  float* As = SB;
  float* Cs = SB;
  const int tid = threadIdx.x;
  const int b = blockIdx.y;
  const int i0b = blockIdx.x * ITILE;

  // ---- stage X[b] into LDS (row t contiguous, pitch 129) ----
  const float* Xb = X + b * (Tq * Fq);
#pragma unroll
  for (int it = 0; it < 8; ++it) {
    const int e = tid + it * 512;
    const int t = e >> 5;                // 32 float4 per 128-float row
    const int f4 = e & 31;
    const float4 v = reinterpret_cast<const float4*>(Xb)[e];
    float* d = &Xs[t * PITCH + f4 * 4];
    d[0] = v.x; d[1] = v.y; d[2] = v.z; d[3] = v.w;
  }
  __syncthreads();

  const int lane = tid & 63;
  const int wv = tid >> 6;               // 0..7
  const int iL = wv * 2;                 // wave's i_local base (2 i per wave)
  const int i0 = __builtin_amdgcn_readfirstlane(i0b + iL);

  // ---- stage 1: logits for i0, i0+1 at t = lane, lane+64 ----
  float a0[2] = {0.f, 0.f}, a1[2] = {0.f, 0.f};
  const float* Wp = Wd + i0;             // Wd[f][i] at f*Tq + i (top F rows)
  const float* xr0 = &Xs[lane * PITCH];
  const float* xr1 = &Xs[(lane + 64) * PITCH];
#pragma unroll 8
  for (int f = 0; f < Fq; ++f) {
    const float x0 = xr0[f];
    const float x1 = xr1[f];
    const float* wr = Wp + f * Tq;       // uniform -> s_load_dwordx2
#pragma unroll
    for (int j = 0; j < 2; ++j) {
      const float w = wr[j];
      a0[j] = fmaf(x0, w, a0[j]);
      a1[j] = fmaf(x1, w, a1[j]);
    }
  }

  // ---- softmax over t (wave holds all 128 t) ----
  float p0[2], p1[2];
#pragma unroll
  for (int j = 0; j < 2; ++j) {
    float m = fmaxf(a0[j], a1[j]);
#pragma unroll
    for (int d = 1; d < 64; d <<= 1) m = fmaxf(m, __shfl_xor(m, d, 64));
    const float e0 = __expf(a0[j] - m);
    const float e1 = __expf(a1[j] - m);
    float s = e0 + e1;
#pragma unroll
    for (int d = 1; d < 64; d <<= 1) s += __shfl_xor(s, d, 64);
    const float inv = 1.0f / s;
    p0[j] = e0 * inv;
    p1[j] = e1 * inv;
  }

  // ---- transpose alpha through LDS: As[t][iL..iL+1] (8B-aligned) ----
  *reinterpret_cast<float2*>(&As[lane * APITCH + iL]) = make_float2(p0[0], p0[1]);
  *reinterpret_cast<float2*>(&As[(lane + 64) * APITCH + iL]) =
      make_float2(p1[0], p1[1]);
  __syncthreads();

  // ---- stage 2: C[i,f] = sum_t alpha[t,i] * Xs[t][f]; lanes <-> f ----
  float c0[2] = {0.f, 0.f}, c1[2] = {0.f, 0.f};
#pragma unroll 8
  for (int t = 0; t < Tq; ++t) {
    const float2 a2 = *reinterpret_cast<const float2*>(&As[t * APITCH + iL]);
    const float aa[2] = {a2.x, a2.y};    // wave-uniform broadcast
    const float x0 = Xs[t * PITCH + lane];
    const float x1 = Xs[t * PITCH + lane + 64];
#pragma unroll
    for (int j = 0; j < 2; ++j) {
      c0[j] = fmaf(aa[j], x0, c0[j]);
      c1[j] = fmaf(aa[j], x1, c1[j]);
    }
  }
  __syncthreads();  // all As reads done before Cs overwrites the union buffer
#pragma unroll
  for (int j = 0; j < 2; ++j) {
    Cs[(iL + j) * CPITCH + lane] = c0[j];
    Cs[(iL + j) * CPITCH + lane + 64] = c1[j];
  }
  __syncthreads();

  // ---- gate GEMM + activations.
  //      thread -> u = (wv&3)*32 + (lane&31);
  //                i-group ig = (wv>>2)*2 + (lane>>5): rows ig*4..ig*4+3 ----
  const int uu = lane & 31;
  const int ub = (wv & 3) * 32 + uu;
  const int ig = ((wv >> 2) << 1) | (lane >> 5);
  const int ih = ig * 4;
  float zi[4] = {0.f, 0.f, 0.f, 0.f};
  float zc[4] = {0.f, 0.f, 0.f, 0.f};
  float zo[4] = {0.f, 0.f, 0.f, 0.f};

  const float* WkP = Wk + ub;            // Wk[f][n] at f*4U + n
  for (int f = 0; f < Fq; f += 4) {
    float4 cr[4];
#pragma unroll
    for (int j = 0; j < 4; ++j)          // b128 broadcast (2 addrs/wave: free)
      cr[j] = *reinterpret_cast<const float4*>(&Cs[(ih + j) * CPITCH + f]);
#pragma unroll
    for (int ff = 0; ff < 4; ++ff) {
      const float* wf = WkP + (f + ff) * (4 * Uq);
      const float wi = wf[0];            // coalesced dword loads (L2-resident)
      const float wc = wf[2 * Uq];
      const float wo = wf[3 * Uq];
#pragma unroll
      for (int j = 0; j < 4; ++j) {
        const float cv = (&cr[j].x)[ff];
        zi[j] = fmaf(cv, wi, zi[j]);
        zc[j] = fmaf(cv, wc, zc[j]);
        zo[j] = fmaf(cv, wo, zo[j]);
      }
    }
  }

  const float bi = bl[ub];
  const float bc = bl[2 * Uq + ub];
  const float bo = bl[3 * Uq + ub];
#pragma unroll
  for (int j = 0; j < 4; ++j) {
    const float cc = sigmoid_(zi[j] + bi) * tanh_(zc[j] + bc);
    const float h = sigmoid_(zo[j] + bo) * tanh_(cc);
    out[(b * Tq + i0b + ih + j) * Uq + ub] = h;
  }
}

}  // namespace

extern "C" void kernel_launch(void* const* d_in, const int* in_sizes, int n_in,
                              void* d_out, int out_size, void* d_ws, size_t ws_size,
                              hipStream_t stream) {
  const float* X  = (const float*)d_in[0];   // (B, T, F)
  const float* Wd = (const float*)d_in[1];   // (F+U, T); only rows [0,F) matter
  // d_in[2] = bd: constant along softmax axis -> cancels, unused
  const float* Wk = (const float*)d_in[3];   // (F, 4U)
  // d_in[4] = Wr: multiplied by h0 == 0 -> unused
  const float* bl = (const float*)d_in[5];   // (4U,)
  float* out = (float*)d_out;                // (B, T, U) fp32

  k_all<<<dim3(8, 32), 512, 0, stream>>>(X, Wd, Wk, bl, out);
}